// Round 15
// baseline (433.668 us; speedup 1.0000x reference)
//
#include <hip/hip_runtime.h>

#define N_NODES 100000
#define D_IN 32
#define D_HID 64
#define D_OUT 32
#define NBUCK 391      // ceil(N_NODES/256)
#define CHUNK 8192     // edges per partition block
#define CAP   8192     // localfill LDS image capacity (ints)

typedef unsigned short ushort8v __attribute__((ext_vector_type(8)));
typedef unsigned short ushort4v __attribute__((ext_vector_type(4)));

__device__ __forceinline__ float bf2f(unsigned short u) {
    return __uint_as_float((unsigned)u << 16);
}
__device__ __forceinline__ unsigned short f2bf(float f) {
    unsigned u = __float_as_uint(f);
    return (unsigned short)((u + 0x7FFF + ((u >> 16) & 1)) >> 16);   // RTN-even
}

// ---------------- zero the 1024 bucket counters ----------------
__global__ void zero_counts_kernel(int* __restrict__ p) {
    p[blockIdx.x * 256 + threadIdx.x] = 0;
}

// ---------------- bucket-level histograms (LDS-staged) ----------------
__global__ __launch_bounds__(256) void bucket_hist_kernel(
    const int* __restrict__ src, const int* __restrict__ dst,
    int* __restrict__ sb_cnt, int* __restrict__ db_cnt, int E) {
    __shared__ int hs[NBUCK], hd[NBUCK];
    int tid = threadIdx.x;
    for (int i = tid; i < NBUCK; i += 256) { hs[i] = 0; hd[i] = 0; }
    __syncthreads();
    int stride = gridDim.x * 256;
    for (int e = blockIdx.x * 256 + tid; e < E; e += stride) {
        atomicAdd(&hs[src[e] >> 8], 1);
        atomicAdd(&hd[dst[e] >> 8], 1);
    }
    __syncthreads();
    for (int i = tid; i < NBUCK; i += 256) {
        if (hs[i]) atomicAdd(&sb_cnt[i], hs[i]);
        if (hd[i]) atomicAdd(&db_cnt[i], hd[i]);
    }
}

// ---------------- single-block scan of both bucket counters; zeroes sb_cnt for reuse ----------------
__global__ __launch_bounds__(512) void bucket_scan_kernel(
    int* __restrict__ sb_cnt, const int* __restrict__ db_cnt,
    int* __restrict__ sb_base, int* __restrict__ db_base,
    int* __restrict__ sb_cur, int* __restrict__ db_cur, int E) {
    __shared__ int s[512];
    int tid = threadIdx.x;
    int v = (tid < NBUCK) ? sb_cnt[tid] : 0;
    s[tid] = v;
    __syncthreads();
    for (int off = 1; off < 512; off <<= 1) {
        int tv = (tid >= off) ? s[tid - off] : 0;
        __syncthreads(); s[tid] += tv; __syncthreads();
    }
    if (tid < NBUCK) { int e0 = s[tid] - v; sb_base[tid] = e0; sb_cur[tid] = e0; }
    if (tid == 0) sb_base[NBUCK] = E;
    __syncthreads();
    int v2 = (tid < NBUCK) ? db_cnt[tid] : 0;
    s[tid] = v2;
    __syncthreads();
    for (int off = 1; off < 512; off <<= 1) {
        int tv = (tid >= off) ? s[tid - off] : 0;
        __syncthreads(); s[tid] += tv; __syncthreads();
    }
    if (tid < NBUCK) { int e0 = s[tid] - v2; db_base[tid] = e0; db_cur[tid] = e0; }
    if (tid == 0) db_base[NBUCK] = E;
    __syncthreads();
    sb_cnt[tid] = 0;   // freed: becomes the 256-bin degree histogram (+cursors)
}

// ---------------- merged LDS multisplit: dst->ebuf (packed), src->sbuf (bytes) ----------------
__global__ __launch_bounds__(512) void partition_both_kernel(
    const int* __restrict__ src, const int* __restrict__ dst,
    int* __restrict__ sb_cur, int* __restrict__ db_cur,
    int* __restrict__ ebuf, unsigned char* __restrict__ sbuf, int E) {
    __shared__ int dh[NBUCK], sh_[NBUCK];
    __shared__ int sarr[512];
    __shared__ int dloff[NBUCK], dgb[NBUCK], dcur[NBUCK];
    __shared__ int sloff[NBUCK], sgb[NBUCK], scur[NBUCK];
    __shared__ int dbuf[CHUNK];
    __shared__ unsigned char sbytes[CHUNK];
    int tid = threadIdx.x;
    int base = blockIdx.x * CHUNK;
    int lim = E - base; if (lim > CHUNK) lim = CHUNK;

    for (int i = tid; i < NBUCK; i += 512) { dh[i] = 0; sh_[i] = 0; }
    __syncthreads();
    for (int k = tid; k < lim; k += 512) {
        atomicAdd(&dh[dst[base + k] >> 8], 1);
        atomicAdd(&sh_[src[base + k] >> 8], 1);
    }
    __syncthreads();
    int v = (tid < NBUCK) ? dh[tid] : 0;
    sarr[tid] = v;
    __syncthreads();
    for (int off = 1; off < 512; off <<= 1) {
        int tv = (tid >= off) ? sarr[tid - off] : 0;
        __syncthreads(); sarr[tid] += tv; __syncthreads();
    }
    if (tid < NBUCK) {
        int excl = sarr[tid] - v;
        dloff[tid] = excl; dcur[tid] = excl;
        dgb[tid] = v ? atomicAdd(&db_cur[tid], v) : 0;
    }
    __syncthreads();
    int v2 = (tid < NBUCK) ? sh_[tid] : 0;
    sarr[tid] = v2;
    __syncthreads();
    for (int off = 1; off < 512; off <<= 1) {
        int tv = (tid >= off) ? sarr[tid - off] : 0;
        __syncthreads(); sarr[tid] += tv; __syncthreads();
    }
    if (tid < NBUCK) {
        int excl = sarr[tid] - v2;
        sloff[tid] = excl; scur[tid] = excl;
        sgb[tid] = v2 ? atomicAdd(&sb_cur[tid], v2) : 0;
    }
    __syncthreads();
    for (int k = tid; k < lim; k += 512) {
        int d = dst[base + k], s0 = src[base + k];
        int p = atomicAdd(&dcur[d >> 8], 1);
        dbuf[p] = (s0 << 8) | (d & 255);
        int p2 = atomicAdd(&scur[s0 >> 8], 1);
        sbytes[p2] = (unsigned char)(s0 & 255);
    }
    __syncthreads();
    int w = tid >> 6, lane = tid & 63;
    for (int b = w; b < NBUCK; b += 8) {
        int st = dloff[b], len = dh[b], gb = dgb[b];
        for (int i = lane; i < len; i += 64) ebuf[gb + i] = dbuf[st + i];
        int st2 = sloff[b], len2 = sh_[b], gb2 = sgb[b];
        for (int i = lane; i < len2; i += 64) sbuf[gb2 + i] = sbytes[st2 + i];
    }
}

// ---------------- per-bucket finalize: norms + prescale + rowptr + colidx + deg-hist ----------------
__global__ __launch_bounds__(256) void bucket_finalize_kernel(
    const unsigned char* __restrict__ sbuf, const int* __restrict__ sb_base,
    const float4* __restrict__ x4, ushort4v* __restrict__ xs4b,
    float* __restrict__ norm_src,
    const int* __restrict__ ebuf, const int* __restrict__ db_base,
    int* __restrict__ rowptr, float* __restrict__ norm_dst,
    int* __restrict__ colidx, int* __restrict__ dbins, int n_nodes, int E) {
    __shared__ int limg[CAP];
    __shared__ int cnt[256];
    __shared__ int sc[256];
    __shared__ float nsl[256];
    __shared__ int dbh[256];
    int b = blockIdx.x, tid = threadIdx.x;
    int base_node = b << 8;
    int nn = n_nodes - base_node; if (nn > 256) nn = 256;

    // ---- phase 1: src degree -> norm_src + xs prescale ----
    int st = sb_base[b], en = sb_base[b + 1];
    cnt[tid] = 0;
    dbh[tid] = 0;
    __syncthreads();
    for (int k = st + tid; k < en; k += 256) atomicAdd(&cnt[sbuf[k]], 1);
    __syncthreads();
    if (tid < nn) {
        int d = cnt[tid];
        float ns = rsqrtf((float)(d < 1 ? 1 : d));
        norm_src[base_node + tid] = ns;
        nsl[tid] = ns;
    }
    __syncthreads();
    for (int k = tid; k < nn * 8; k += 256) {
        float4 v = x4[((long)base_node << 3) + k];
        float s = nsl[k >> 3];
        ushort4v o;
        o[0] = f2bf(v.x * s); o[1] = f2bf(v.y * s);
        o[2] = f2bf(v.z * s); o[3] = f2bf(v.w * s);
        xs4b[((long)base_node << 3) + k] = o;
    }

    // ---- phase 2: dst degree -> rowptr/norm_dst, colidx fill, degree histogram ----
    int cbase = db_base[b], cend = db_base[b + 1];
    int len = cend - cbase;
    __syncthreads();
    cnt[tid] = 0;
    __syncthreads();
    for (int k = tid; k < len; k += 256) atomicAdd(&cnt[ebuf[cbase + k] & 255], 1);
    __syncthreads();
    int v = cnt[tid];
    sc[tid] = v;
    __syncthreads();
    for (int off = 1; off < 256; off <<= 1) {
        int tv = (tid >= off) ? sc[tid - off] : 0;
        __syncthreads(); sc[tid] += tv; __syncthreads();
    }
    int excl = sc[tid] - v;
    if (tid < nn) {
        rowptr[base_node + tid] = cbase + excl;
        norm_dst[base_node + tid] = rsqrtf((float)(v < 1 ? 1 : v));
        atomicAdd(&dbh[v < 255 ? v : 255], 1);   // LDS degree histogram
    }
    if (b == NBUCK - 1 && tid == 0) rowptr[n_nodes] = E;
    __syncthreads();
    if (dbh[tid]) atomicAdd(&dbins[tid], dbh[tid]);
    cnt[tid] = excl;   // reuse as local cursor
    __syncthreads();
    if (len <= CAP) {
        for (int k = tid; k < len; k += 256) {
            int v2 = ebuf[cbase + k];
            int p = atomicAdd(&cnt[v2 & 255], 1);
            limg[p] = v2 >> 8;
        }
        __syncthreads();
        for (int k = tid; k < len; k += 256) colidx[cbase + k] = limg[k];
    } else {
        for (int k = tid; k < len; k += 256) {
            int v2 = ebuf[cbase + k];
            int p = atomicAdd(&cnt[v2 & 255], 1);
            colidx[cbase + p] = v2 >> 8;
        }
    }
}

// ---------------- degree-bin scan: bins -> exclusive bases (in-place, become cursors) ----------------
__global__ __launch_bounds__(256) void deg_scan_kernel(int* __restrict__ bins) {
    __shared__ int s[256];
    int tid = threadIdx.x;
    int v = bins[tid];
    s[tid] = v;
    __syncthreads();
    for (int off = 1; off < 256; off <<= 1) {
        int tv = (tid >= off) ? s[tid - off] : 0;
        __syncthreads(); s[tid] += tv; __syncthreads();
    }
    bins[tid] = s[tid] - v;   // exclusive base = initial cursor
}

// ---------------- place nodes into perm, degree-sorted ----------------
__global__ __launch_bounds__(256) void place_perm_kernel(
    const int* __restrict__ rowptr, int* __restrict__ cursor,
    int* __restrict__ perm, int n_nodes) {
    int n = blockIdx.x * 256 + threadIdx.x;
    if (n < n_nodes) {
        int d = rowptr[n + 1] - rowptr[n];
        int b = d < 255 ? d : 255;
        int p = atomicAdd(&cursor[b], 1);
        perm[p] = n;
    }
}

// ---------------- pure gather 1: 4 degree-matched nodes/wave -> agg f32 ----------------
__global__ __launch_bounds__(256) void gather1_kernel(
    const ushort8v* __restrict__ xs8, const int* __restrict__ colidx,
    const int* __restrict__ rowptr, const int* __restrict__ perm,
    float* __restrict__ agg, int n_nodes) {
    int t = threadIdx.x;
    int w = t >> 6, lane = t & 63;
    int quarter = lane >> 4, ql = lane & 15;
    int eh = ql >> 2, q = ql & 3;
    int qb = quarter << 4;
    int nquads = (n_nodes + 3) >> 2;

    for (int p = blockIdx.x * 4 + w; p < nquads; p += gridDim.x * 4) {
        int nidx = (p << 2) + quarter;
        bool valid = nidx < n_nodes;
        int node = valid ? perm[nidx] : 0;
        int myS = rowptr[node];
        int myD = valid ? rowptr[node + 1] - myS : 0;
        int dm = myD;
        dm = max(dm, __shfl_xor(dm, 16));
        dm = max(dm, __shfl_xor(dm, 32));
        float a[8];
#pragma unroll
        for (int r = 0; r < 8; ++r) a[r] = 0.f;
        for (int base = 0; base < dm; base += 16) {
            int mylim = myD - base; mylim = mylim < 0 ? 0 : (mylim > 16 ? 16 : mylim);
            int c_reg = (ql < mylim) ? colidx[myS + base + ql] : 0;
            int c0 = __shfl(c_reg, qb | eh);
            int c1 = __shfl(c_reg, qb | (eh + 4));
            int c2 = __shfl(c_reg, qb | (eh + 8));
            int c3 = __shfl(c_reg, qb | (eh + 12));
            ushort8v v0 = xs8[(long)c0 * 4 + q];
            ushort8v v1 = xs8[(long)c1 * 4 + q];
            ushort8v v2 = xs8[(long)c2 * 4 + q];
            ushort8v v3 = xs8[(long)c3 * 4 + q];
            float m0 = (eh      < mylim) ? 1.f : 0.f;
            float m1 = (eh +  4 < mylim) ? 1.f : 0.f;
            float m2 = (eh +  8 < mylim) ? 1.f : 0.f;
            float m3 = (eh + 12 < mylim) ? 1.f : 0.f;
#pragma unroll
            for (int r = 0; r < 8; ++r) {
                a[r] = fmaf(bf2f(v0[r]), m0, a[r]);
                a[r] = fmaf(bf2f(v1[r]), m1, a[r]);
                a[r] = fmaf(bf2f(v2[r]), m2, a[r]);
                a[r] = fmaf(bf2f(v3[r]), m3, a[r]);
            }
        }
#pragma unroll
        for (int r = 0; r < 8; ++r) { a[r] += __shfl_xor(a[r], 4); a[r] += __shfl_xor(a[r], 8); }
        if (ql < 4 && valid) {
            float* orow = agg + (long)node * 32 + ql * 8;
            float4 o1, o2;
            o1.x = a[0]; o1.y = a[1]; o1.z = a[2]; o1.w = a[3];
            o2.x = a[4]; o2.y = a[5]; o2.z = a[6]; o2.w = a[7];
            ((float4*)orow)[0] = o1;
            ((float4*)orow)[1] = o2;
        }
    }
}

// ---------------- dense fused GEMMs: ybf = bf16( ns * ((nd*(agg@W1)+b1) @ W2) ) ----------------
__global__ __launch_bounds__(256) void gemm_fused_kernel(
    const float* __restrict__ agg, const float* __restrict__ norm_src,
    const float* __restrict__ norm_dst,
    const float* __restrict__ W1, const float* __restrict__ b1,
    const float* __restrict__ W2, unsigned short* __restrict__ ybf, int n_nodes) {
    __shared__ float W1s[D_IN * D_HID];
    __shared__ float W2s[D_HID * D_OUT];
    __shared__ float b1s[D_HID];
    __shared__ float accs[4][2][D_IN];
    __shared__ float z1s[4][2][D_HID];
    int t = threadIdx.x;
    for (int i = t; i < 2048; i += 256) { W1s[i] = W1[i]; W2s[i] = W2[i]; }
    if (t < D_HID) b1s[t] = b1[t];
    __syncthreads();
    int w = t >> 6, lane = t & 63;
    int half = lane >> 5, hl = lane & 31;
    int npairs = (n_nodes + 1) >> 1;
    for (int p = blockIdx.x * 4 + w; p < npairs; p += gridDim.x * 4) {
        int nA = 2 * p, nB = nA + 1;
        bool hasB = nB < n_nodes;
        int nh = half ? (hasB ? nB : nA) : nA;
        accs[w][half][hl] = agg[(long)nh * 32 + hl];   // same-wave LDS
        float ndA = norm_dst[nA], ndB = hasB ? norm_dst[nB] : 0.f;
        float s1A = 0.f, s1B = 0.f;
#pragma unroll
        for (int k = 0; k < D_IN; ++k) {
            float wv = W1s[k * D_HID + lane];
            s1A = fmaf(accs[w][0][k], wv, s1A);
            s1B = fmaf(accs[w][1][k], wv, s1B);
        }
        z1s[w][0][lane] = ndA * s1A + b1s[lane];
        z1s[w][1][lane] = ndB * s1B + b1s[lane];
        float s2 = 0.f;
#pragma unroll
        for (int k = 0; k < D_HID; ++k) s2 = fmaf(z1s[w][half][k], W2s[k * D_OUT + hl], s2);
        int n_ = half ? nB : nA;
        if (!half || hasB) ybf[(long)n_ * 32 + hl] = f2bf(norm_src[n_] * s2);
    }
}

// ---------------- pure gather 2: 4 degree-matched nodes/wave -> out = nd*sum + b2 ----------------
__global__ __launch_bounds__(256) void gather2_kernel(
    const ushort8v* __restrict__ y8, const int* __restrict__ colidx,
    const int* __restrict__ rowptr, const int* __restrict__ perm,
    const float* __restrict__ norm_dst,
    const float* __restrict__ b2, float* __restrict__ out, int n_nodes) {
    int t = threadIdx.x;
    int w = t >> 6, lane = t & 63;
    int quarter = lane >> 4, ql = lane & 15;
    int eh = ql >> 2, q = ql & 3;
    int qb = quarter << 4;
    int nquads = (n_nodes + 3) >> 2;

    for (int p = blockIdx.x * 4 + w; p < nquads; p += gridDim.x * 4) {
        int nidx = (p << 2) + quarter;
        bool valid = nidx < n_nodes;
        int node = valid ? perm[nidx] : 0;
        int myS = rowptr[node];
        int myD = valid ? rowptr[node + 1] - myS : 0;
        int dm = myD;
        dm = max(dm, __shfl_xor(dm, 16));
        dm = max(dm, __shfl_xor(dm, 32));
        float a[8];
#pragma unroll
        for (int r = 0; r < 8; ++r) a[r] = 0.f;
        for (int base = 0; base < dm; base += 16) {
            int mylim = myD - base; mylim = mylim < 0 ? 0 : (mylim > 16 ? 16 : mylim);
            int c_reg = (ql < mylim) ? colidx[myS + base + ql] : 0;
            int c0 = __shfl(c_reg, qb | eh);
            int c1 = __shfl(c_reg, qb | (eh + 4));
            int c2 = __shfl(c_reg, qb | (eh + 8));
            int c3 = __shfl(c_reg, qb | (eh + 12));
            ushort8v v0 = y8[(long)c0 * 4 + q];
            ushort8v v1 = y8[(long)c1 * 4 + q];
            ushort8v v2 = y8[(long)c2 * 4 + q];
            ushort8v v3 = y8[(long)c3 * 4 + q];
            float m0 = (eh      < mylim) ? 1.f : 0.f;
            float m1 = (eh +  4 < mylim) ? 1.f : 0.f;
            float m2 = (eh +  8 < mylim) ? 1.f : 0.f;
            float m3 = (eh + 12 < mylim) ? 1.f : 0.f;
#pragma unroll
            for (int r = 0; r < 8; ++r) {
                a[r] = fmaf(bf2f(v0[r]), m0, a[r]);
                a[r] = fmaf(bf2f(v1[r]), m1, a[r]);
                a[r] = fmaf(bf2f(v2[r]), m2, a[r]);
                a[r] = fmaf(bf2f(v3[r]), m3, a[r]);
            }
        }
#pragma unroll
        for (int r = 0; r < 8; ++r) { a[r] += __shfl_xor(a[r], 4); a[r] += __shfl_xor(a[r], 8); }
        if (ql < 4 && valid) {
            float nd = norm_dst[node];
            const float4 bL = ((const float4*)b2)[ql * 2];
            const float4 bH = ((const float4*)b2)[ql * 2 + 1];
            float4 o1, o2;
            o1.x = fmaf(a[0], nd, bL.x); o1.y = fmaf(a[1], nd, bL.y);
            o1.z = fmaf(a[2], nd, bL.z); o1.w = fmaf(a[3], nd, bL.w);
            o2.x = fmaf(a[4], nd, bH.x); o2.y = fmaf(a[5], nd, bH.y);
            o2.z = fmaf(a[6], nd, bH.z); o2.w = fmaf(a[7], nd, bH.w);
            float* orow = out + (long)node * 32 + ql * 8;
            ((float4*)orow)[0] = o1;
            ((float4*)orow)[1] = o2;
        }
    }
}

extern "C" void kernel_launch(void* const* d_in, const int* in_sizes, int n_in,
                              void* d_out, int out_size, void* d_ws, size_t ws_size,
                              hipStream_t stream) {
    const float* x   = (const float*)d_in[0];
    const int*   src = (const int*)d_in[1];
    const int*   dst = (const int*)d_in[2];
    const float* W1  = (const float*)d_in[3];
    const float* b1  = (const float*)d_in[4];
    const float* W2  = (const float*)d_in[5];
    const float* b2  = (const float*)d_in[6];

    const int N = N_NODES;
    const int E = in_sizes[1];   // 1,600,000

    // workspace (int offsets; all gather/row buffers 64B-aligned):
    int* ws_i    = (int*)d_ws;
    int* sb_cnt  = ws_i;                           // [512]; reused as deg bins+cursors
    int* db_cnt  = ws_i + 512;
    int* sb_base = ws_i + 1024;
    int* db_base = ws_i + 1536;
    int* sb_cur  = ws_i + 2048;
    int* db_cur  = ws_i + 2560;
    int* rowptr  = ws_i + 3072;                    // [N+1, padded to 100032]
    int* colidx  = ws_i + 103104;                  // [E]
    float* norms = (float*)(ws_i + 1703104);       // [2N]
    int* ebuf    = ws_i + 1903104;                 // [E] ints, 64B-aligned (ybf overlay)
    unsigned char* sbuf = (unsigned char*)(ws_i + 3503104);   // [E] bytes
    unsigned short* xsb = (unsigned short*)(ws_i + 3903104);  // [32N] bf16, 64B-aligned
    float* agg   = (float*)(ws_i + 5503104);       // [32N] f32
    int* perm    = ws_i + 8703104;                 // [N]
    unsigned short* ybf = (unsigned short*)ebuf;

    zero_counts_kernel<<<4, 256, 0, stream>>>(ws_i);

    bucket_hist_kernel<<<256, 256, 0, stream>>>(src, dst, sb_cnt, db_cnt, E);
    bucket_scan_kernel<<<1, 512, 0, stream>>>(sb_cnt, db_cnt, sb_base, db_base,
                                              sb_cur, db_cur, E);

    int pb = (E + CHUNK - 1) / CHUNK;      // 196 blocks
    partition_both_kernel<<<pb, 512, 0, stream>>>(src, dst, sb_cur, db_cur,
                                                  ebuf, sbuf, E);
    bucket_finalize_kernel<<<NBUCK, 256, 0, stream>>>(sbuf, sb_base,
                                                      (const float4*)x, (ushort4v*)xsb,
                                                      norms, ebuf, db_base, rowptr,
                                                      norms + N, colidx, sb_cnt, N, E);

    deg_scan_kernel<<<1, 256, 0, stream>>>(sb_cnt);
    place_perm_kernel<<<NBUCK, 256, 0, stream>>>(rowptr, sb_cnt, perm, N);

    gather1_kernel<<<2048, 256, 0, stream>>>((const ushort8v*)xsb, colidx, rowptr,
                                             perm, agg, N);
    gemm_fused_kernel<<<2048, 256, 0, stream>>>(agg, norms, norms + N,
                                                W1, b1, W2, ybf, N);
    gather2_kernel<<<2048, 256, 0, stream>>>((const ushort8v*)ybf, colidx, rowptr,
                                             perm, norms + N, b2, (float*)d_out, N);
}

// Round 16
// 180.366 us; speedup vs baseline: 2.4044x; 2.4044x over previous
//
#include <hip/hip_runtime.h>

#define N_NODES 100000
#define D_IN 32
#define D_HID 64
#define D_OUT 32
#define NBUCK 391      // ceil(N_NODES/256)
#define CHUNK 8192     // edges per partition block
#define CAP   8192     // localfill LDS image capacity (ints)

typedef unsigned short ushort8v __attribute__((ext_vector_type(8)));
typedef unsigned short ushort4v __attribute__((ext_vector_type(4)));

__device__ __forceinline__ float bf2f(unsigned short u) {
    return __uint_as_float((unsigned)u << 16);
}
__device__ __forceinline__ unsigned short f2bf(float f) {
    unsigned u = __float_as_uint(f);
    return (unsigned short)((u + 0x7FFF + ((u >> 16) & 1)) >> 16);   // RTN-even
}

// ---------------- zero the 1024 bucket counters ----------------
__global__ void zero_counts_kernel(int* __restrict__ p) {
    p[blockIdx.x * 256 + threadIdx.x] = 0;
}

// ---------------- bucket-level histograms (LDS-staged) ----------------
__global__ __launch_bounds__(256) void bucket_hist_kernel(
    const int* __restrict__ src, const int* __restrict__ dst,
    int* __restrict__ sb_cnt, int* __restrict__ db_cnt, int E) {
    __shared__ int hs[NBUCK], hd[NBUCK];
    int tid = threadIdx.x;
    for (int i = tid; i < NBUCK; i += 256) { hs[i] = 0; hd[i] = 0; }
    __syncthreads();
    int stride = gridDim.x * 256;
    for (int e = blockIdx.x * 256 + tid; e < E; e += stride) {
        atomicAdd(&hs[src[e] >> 8], 1);
        atomicAdd(&hd[dst[e] >> 8], 1);
    }
    __syncthreads();
    for (int i = tid; i < NBUCK; i += 256) {
        if (hs[i]) atomicAdd(&sb_cnt[i], hs[i]);
        if (hd[i]) atomicAdd(&db_cnt[i], hd[i]);
    }
}

// ---------------- single-block scan of both bucket counters; zeroes sb_cnt for reuse ----------------
__global__ __launch_bounds__(512) void bucket_scan_kernel(
    int* __restrict__ sb_cnt, const int* __restrict__ db_cnt,
    int* __restrict__ sb_base, int* __restrict__ db_base,
    int* __restrict__ sb_cur, int* __restrict__ db_cur, int E) {
    __shared__ int s[512];
    int tid = threadIdx.x;
    int v = (tid < NBUCK) ? sb_cnt[tid] : 0;
    s[tid] = v;
    __syncthreads();
    for (int off = 1; off < 512; off <<= 1) {
        int tv = (tid >= off) ? s[tid - off] : 0;
        __syncthreads(); s[tid] += tv; __syncthreads();
    }
    if (tid < NBUCK) { int e0 = s[tid] - v; sb_base[tid] = e0; sb_cur[tid] = e0; }
    if (tid == 0) sb_base[NBUCK] = E;
    __syncthreads();
    int v2 = (tid < NBUCK) ? db_cnt[tid] : 0;
    s[tid] = v2;
    __syncthreads();
    for (int off = 1; off < 512; off <<= 1) {
        int tv = (tid >= off) ? s[tid - off] : 0;
        __syncthreads(); s[tid] += tv; __syncthreads();
    }
    if (tid < NBUCK) { int e0 = s[tid] - v2; db_base[tid] = e0; db_cur[tid] = e0; }
    if (tid == 0) db_base[NBUCK] = E;
    __syncthreads();
    sb_cnt[tid] = 0;   // freed: becomes the 256-bin degree histogram (+cursors)
}

// ---------------- merged LDS multisplit: dst->ebuf (packed), src->sbuf (bytes) ----------------
__global__ __launch_bounds__(512) void partition_both_kernel(
    const int* __restrict__ src, const int* __restrict__ dst,
    int* __restrict__ sb_cur, int* __restrict__ db_cur,
    int* __restrict__ ebuf, unsigned char* __restrict__ sbuf, int E) {
    __shared__ int dh[NBUCK], sh_[NBUCK];
    __shared__ int sarr[512];
    __shared__ int dloff[NBUCK], dgb[NBUCK], dcur[NBUCK];
    __shared__ int sloff[NBUCK], sgb[NBUCK], scur[NBUCK];
    __shared__ int dbuf[CHUNK];
    __shared__ unsigned char sbytes[CHUNK];
    int tid = threadIdx.x;
    int base = blockIdx.x * CHUNK;
    int lim = E - base; if (lim > CHUNK) lim = CHUNK;

    for (int i = tid; i < NBUCK; i += 512) { dh[i] = 0; sh_[i] = 0; }
    __syncthreads();
    for (int k = tid; k < lim; k += 512) {
        atomicAdd(&dh[dst[base + k] >> 8], 1);
        atomicAdd(&sh_[src[base + k] >> 8], 1);
    }
    __syncthreads();
    int v = (tid < NBUCK) ? dh[tid] : 0;
    sarr[tid] = v;
    __syncthreads();
    for (int off = 1; off < 512; off <<= 1) {
        int tv = (tid >= off) ? sarr[tid - off] : 0;
        __syncthreads(); sarr[tid] += tv; __syncthreads();
    }
    if (tid < NBUCK) {
        int excl = sarr[tid] - v;
        dloff[tid] = excl; dcur[tid] = excl;
        dgb[tid] = v ? atomicAdd(&db_cur[tid], v) : 0;
    }
    __syncthreads();
    int v2 = (tid < NBUCK) ? sh_[tid] : 0;
    sarr[tid] = v2;
    __syncthreads();
    for (int off = 1; off < 512; off <<= 1) {
        int tv = (tid >= off) ? sarr[tid - off] : 0;
        __syncthreads(); sarr[tid] += tv; __syncthreads();
    }
    if (tid < NBUCK) {
        int excl = sarr[tid] - v2;
        sloff[tid] = excl; scur[tid] = excl;
        sgb[tid] = v2 ? atomicAdd(&sb_cur[tid], v2) : 0;
    }
    __syncthreads();
    for (int k = tid; k < lim; k += 512) {
        int d = dst[base + k], s0 = src[base + k];
        int p = atomicAdd(&dcur[d >> 8], 1);
        dbuf[p] = (s0 << 8) | (d & 255);
        int p2 = atomicAdd(&scur[s0 >> 8], 1);
        sbytes[p2] = (unsigned char)(s0 & 255);
    }
    __syncthreads();
    int w = tid >> 6, lane = tid & 63;
    for (int b = w; b < NBUCK; b += 8) {
        int st = dloff[b], len = dh[b], gb = dgb[b];
        for (int i = lane; i < len; i += 64) ebuf[gb + i] = dbuf[st + i];
        int st2 = sloff[b], len2 = sh_[b], gb2 = sgb[b];
        for (int i = lane; i < len2; i += 64) sbuf[gb2 + i] = sbytes[st2 + i];
    }
}

// ---------------- per-bucket finalize: norms + prescale + rowptr + colidx ----------------
__global__ __launch_bounds__(256) void bucket_finalize_kernel(
    const unsigned char* __restrict__ sbuf, const int* __restrict__ sb_base,
    const float4* __restrict__ x4, ushort4v* __restrict__ xs4b,
    float* __restrict__ norm_src,
    const int* __restrict__ ebuf, const int* __restrict__ db_base,
    int* __restrict__ rowptr, float* __restrict__ norm_dst,
    int* __restrict__ colidx, int n_nodes, int E) {
    __shared__ int limg[CAP];
    __shared__ int cnt[256];
    __shared__ int sc[256];
    __shared__ float nsl[256];
    int b = blockIdx.x, tid = threadIdx.x;
    int base_node = b << 8;
    int nn = n_nodes - base_node; if (nn > 256) nn = 256;

    // ---- phase 1: src degree -> norm_src + xs prescale ----
    int st = sb_base[b], en = sb_base[b + 1];
    cnt[tid] = 0;
    __syncthreads();
    for (int k = st + tid; k < en; k += 256) atomicAdd(&cnt[sbuf[k]], 1);
    __syncthreads();
    if (tid < nn) {
        int d = cnt[tid];
        float ns = rsqrtf((float)(d < 1 ? 1 : d));
        norm_src[base_node + tid] = ns;
        nsl[tid] = ns;
    }
    __syncthreads();
    for (int k = tid; k < nn * 8; k += 256) {
        float4 v = x4[((long)base_node << 3) + k];
        float s = nsl[k >> 3];
        ushort4v o;
        o[0] = f2bf(v.x * s); o[1] = f2bf(v.y * s);
        o[2] = f2bf(v.z * s); o[3] = f2bf(v.w * s);
        xs4b[((long)base_node << 3) + k] = o;
    }

    // ---- phase 2: dst degree -> rowptr/norm_dst, colidx fill ----
    int cbase = db_base[b], cend = db_base[b + 1];
    int len = cend - cbase;
    __syncthreads();
    cnt[tid] = 0;
    __syncthreads();
    for (int k = tid; k < len; k += 256) atomicAdd(&cnt[ebuf[cbase + k] & 255], 1);
    __syncthreads();
    int v = cnt[tid];
    sc[tid] = v;
    __syncthreads();
    for (int off = 1; off < 256; off <<= 1) {
        int tv = (tid >= off) ? sc[tid - off] : 0;
        __syncthreads(); sc[tid] += tv; __syncthreads();
    }
    int excl = sc[tid] - v;
    if (tid < nn) {
        rowptr[base_node + tid] = cbase + excl;
        norm_dst[base_node + tid] = rsqrtf((float)(v < 1 ? 1 : v));
    }
    if (b == NBUCK - 1 && tid == 0) rowptr[n_nodes] = E;
    __syncthreads();
    cnt[tid] = excl;   // reuse as local cursor
    __syncthreads();
    if (len <= CAP) {
        for (int k = tid; k < len; k += 256) {
            int v2 = ebuf[cbase + k];
            int p = atomicAdd(&cnt[v2 & 255], 1);
            limg[p] = v2 >> 8;
        }
        __syncthreads();
        for (int k = tid; k < len; k += 256) colidx[cbase + k] = limg[k];
    } else {
        for (int k = tid; k < len; k += 256) {
            int v2 = ebuf[cbase + k];
            int p = atomicAdd(&cnt[v2 & 255], 1);
            colidx[cbase + p] = v2 >> 8;
        }
    }
}

// ---------------- degree-bin scan: bins -> exclusive bases (in-place, become cursors) ----------------
__global__ __launch_bounds__(256) void deg_scan_kernel(int* __restrict__ bins) {
    __shared__ int s[256];
    int tid = threadIdx.x;
    int v = bins[tid];
    s[tid] = v;
    __syncthreads();
    for (int off = 1; off < 256; off <<= 1) {
        int tv = (tid >= off) ? s[tid - off] : 0;
        __syncthreads(); s[tid] += tv; __syncthreads();
    }
    bins[tid] = s[tid] - v;   // exclusive base = initial cursor
}

// ---------------- degree histogram of dst (LDS-staged; separate cheap pass) ----------------
__global__ __launch_bounds__(256) void deg_hist_kernel(
    const int* __restrict__ rowptr, int* __restrict__ dbins, int n_nodes) {
    __shared__ int h[256];
    int tid = threadIdx.x;
    h[tid] = 0;
    __syncthreads();
    int n = blockIdx.x * 256 + tid;
    if (n < n_nodes) {
        int d = rowptr[n + 1] - rowptr[n];
        atomicAdd(&h[d < 255 ? d : 255], 1);
    }
    __syncthreads();
    if (h[tid]) atomicAdd(&dbins[tid], h[tid]);
}

// ---------------- place nodes into perm, degree-sorted (LDS-staged, low contention) ----------------
__global__ __launch_bounds__(256) void place_perm_kernel(
    const int* __restrict__ rowptr, int* __restrict__ cursor,
    int* __restrict__ perm, int n_nodes) {
    __shared__ int lh[256];   // per-block bin counts
    __shared__ int lb[256];   // per-block global base per bin
    __shared__ int lc[256];   // per-block local cursor
    int tid = threadIdx.x;
    int n = blockIdx.x * 256 + tid;
    lh[tid] = 0;
    lc[tid] = 0;
    __syncthreads();
    int b = -1;
    if (n < n_nodes) {
        int d = rowptr[n + 1] - rowptr[n];
        b = d < 255 ? d : 255;
        atomicAdd(&lh[b], 1);
    }
    __syncthreads();
    int c = lh[tid];
    if (c) lb[tid] = atomicAdd(&cursor[tid], c);   // one global atomic per non-zero bin
    __syncthreads();
    if (n < n_nodes) {
        int r = atomicAdd(&lc[b], 1);              // LDS-local rank
        perm[lb[b] + r] = n;
    }
}

// ---------------- pure gather 1: 4 degree-matched nodes/wave -> agg f32 ----------------
__global__ __launch_bounds__(256) void gather1_kernel(
    const ushort8v* __restrict__ xs8, const int* __restrict__ colidx,
    const int* __restrict__ rowptr, const int* __restrict__ perm,
    float* __restrict__ agg, int n_nodes) {
    int t = threadIdx.x;
    int w = t >> 6, lane = t & 63;
    int quarter = lane >> 4, ql = lane & 15;
    int eh = ql >> 2, q = ql & 3;
    int qb = quarter << 4;
    int nquads = (n_nodes + 3) >> 2;

    for (int p = blockIdx.x * 4 + w; p < nquads; p += gridDim.x * 4) {
        int nidx = (p << 2) + quarter;
        bool valid = nidx < n_nodes;
        int node = valid ? perm[nidx] : 0;
        int myS = rowptr[node];
        int myD = valid ? rowptr[node + 1] - myS : 0;
        int dm = myD;
        dm = max(dm, __shfl_xor(dm, 16));
        dm = max(dm, __shfl_xor(dm, 32));
        float a[8];
#pragma unroll
        for (int r = 0; r < 8; ++r) a[r] = 0.f;
        for (int base = 0; base < dm; base += 16) {
            int mylim = myD - base; mylim = mylim < 0 ? 0 : (mylim > 16 ? 16 : mylim);
            int c_reg = (ql < mylim) ? colidx[myS + base + ql] : 0;
            int c0 = __shfl(c_reg, qb | eh);
            int c1 = __shfl(c_reg, qb | (eh + 4));
            int c2 = __shfl(c_reg, qb | (eh + 8));
            int c3 = __shfl(c_reg, qb | (eh + 12));
            ushort8v v0 = xs8[(long)c0 * 4 + q];
            ushort8v v1 = xs8[(long)c1 * 4 + q];
            ushort8v v2 = xs8[(long)c2 * 4 + q];
            ushort8v v3 = xs8[(long)c3 * 4 + q];
            float m0 = (eh      < mylim) ? 1.f : 0.f;
            float m1 = (eh +  4 < mylim) ? 1.f : 0.f;
            float m2 = (eh +  8 < mylim) ? 1.f : 0.f;
            float m3 = (eh + 12 < mylim) ? 1.f : 0.f;
#pragma unroll
            for (int r = 0; r < 8; ++r) {
                a[r] = fmaf(bf2f(v0[r]), m0, a[r]);
                a[r] = fmaf(bf2f(v1[r]), m1, a[r]);
                a[r] = fmaf(bf2f(v2[r]), m2, a[r]);
                a[r] = fmaf(bf2f(v3[r]), m3, a[r]);
            }
        }
#pragma unroll
        for (int r = 0; r < 8; ++r) { a[r] += __shfl_xor(a[r], 4); a[r] += __shfl_xor(a[r], 8); }
        if (ql < 4 && valid) {
            float* orow = agg + (long)node * 32 + ql * 8;
            float4 o1, o2;
            o1.x = a[0]; o1.y = a[1]; o1.z = a[2]; o1.w = a[3];
            o2.x = a[4]; o2.y = a[5]; o2.z = a[6]; o2.w = a[7];
            ((float4*)orow)[0] = o1;
            ((float4*)orow)[1] = o2;
        }
    }
}

// ---------------- dense fused GEMMs: ybf = bf16( ns * ((nd*(agg@W1)+b1) @ W2) ) ----------------
__global__ __launch_bounds__(256) void gemm_fused_kernel(
    const float* __restrict__ agg, const float* __restrict__ norm_src,
    const float* __restrict__ norm_dst,
    const float* __restrict__ W1, const float* __restrict__ b1,
    const float* __restrict__ W2, unsigned short* __restrict__ ybf, int n_nodes) {
    __shared__ float W1s[D_IN * D_HID];
    __shared__ float W2s[D_HID * D_OUT];
    __shared__ float b1s[D_HID];
    __shared__ float accs[4][2][D_IN];
    __shared__ float z1s[4][2][D_HID];
    int t = threadIdx.x;
    for (int i = t; i < 2048; i += 256) { W1s[i] = W1[i]; W2s[i] = W2[i]; }
    if (t < D_HID) b1s[t] = b1[t];
    __syncthreads();
    int w = t >> 6, lane = t & 63;
    int half = lane >> 5, hl = lane & 31;
    int npairs = (n_nodes + 1) >> 1;
    for (int p = blockIdx.x * 4 + w; p < npairs; p += gridDim.x * 4) {
        int nA = 2 * p, nB = nA + 1;
        bool hasB = nB < n_nodes;
        int nh = half ? (hasB ? nB : nA) : nA;
        accs[w][half][hl] = agg[(long)nh * 32 + hl];   // same-wave LDS
        float ndA = norm_dst[nA], ndB = hasB ? norm_dst[nB] : 0.f;
        float s1A = 0.f, s1B = 0.f;
#pragma unroll
        for (int k = 0; k < D_IN; ++k) {
            float wv = W1s[k * D_HID + lane];
            s1A = fmaf(accs[w][0][k], wv, s1A);
            s1B = fmaf(accs[w][1][k], wv, s1B);
        }
        z1s[w][0][lane] = ndA * s1A + b1s[lane];
        z1s[w][1][lane] = ndB * s1B + b1s[lane];
        float s2 = 0.f;
#pragma unroll
        for (int k = 0; k < D_HID; ++k) s2 = fmaf(z1s[w][half][k], W2s[k * D_OUT + hl], s2);
        int n_ = half ? nB : nA;
        if (!half || hasB) ybf[(long)n_ * 32 + hl] = f2bf(norm_src[n_] * s2);
    }
}

// ---------------- pure gather 2: 4 degree-matched nodes/wave -> out = nd*sum + b2 ----------------
__global__ __launch_bounds__(256) void gather2_kernel(
    const ushort8v* __restrict__ y8, const int* __restrict__ colidx,
    const int* __restrict__ rowptr, const int* __restrict__ perm,
    const float* __restrict__ norm_dst,
    const float* __restrict__ b2, float* __restrict__ out, int n_nodes) {
    int t = threadIdx.x;
    int w = t >> 6, lane = t & 63;
    int quarter = lane >> 4, ql = lane & 15;
    int eh = ql >> 2, q = ql & 3;
    int qb = quarter << 4;
    int nquads = (n_nodes + 3) >> 2;

    for (int p = blockIdx.x * 4 + w; p < nquads; p += gridDim.x * 4) {
        int nidx = (p << 2) + quarter;
        bool valid = nidx < n_nodes;
        int node = valid ? perm[nidx] : 0;
        int myS = rowptr[node];
        int myD = valid ? rowptr[node + 1] - myS : 0;
        int dm = myD;
        dm = max(dm, __shfl_xor(dm, 16));
        dm = max(dm, __shfl_xor(dm, 32));
        float a[8];
#pragma unroll
        for (int r = 0; r < 8; ++r) a[r] = 0.f;
        for (int base = 0; base < dm; base += 16) {
            int mylim = myD - base; mylim = mylim < 0 ? 0 : (mylim > 16 ? 16 : mylim);
            int c_reg = (ql < mylim) ? colidx[myS + base + ql] : 0;
            int c0 = __shfl(c_reg, qb | eh);
            int c1 = __shfl(c_reg, qb | (eh + 4));
            int c2 = __shfl(c_reg, qb | (eh + 8));
            int c3 = __shfl(c_reg, qb | (eh + 12));
            ushort8v v0 = y8[(long)c0 * 4 + q];
            ushort8v v1 = y8[(long)c1 * 4 + q];
            ushort8v v2 = y8[(long)c2 * 4 + q];
            ushort8v v3 = y8[(long)c3 * 4 + q];
            float m0 = (eh      < mylim) ? 1.f : 0.f;
            float m1 = (eh +  4 < mylim) ? 1.f : 0.f;
            float m2 = (eh +  8 < mylim) ? 1.f : 0.f;
            float m3 = (eh + 12 < mylim) ? 1.f : 0.f;
#pragma unroll
            for (int r = 0; r < 8; ++r) {
                a[r] = fmaf(bf2f(v0[r]), m0, a[r]);
                a[r] = fmaf(bf2f(v1[r]), m1, a[r]);
                a[r] = fmaf(bf2f(v2[r]), m2, a[r]);
                a[r] = fmaf(bf2f(v3[r]), m3, a[r]);
            }
        }
#pragma unroll
        for (int r = 0; r < 8; ++r) { a[r] += __shfl_xor(a[r], 4); a[r] += __shfl_xor(a[r], 8); }
        if (ql < 4 && valid) {
            float nd = norm_dst[node];
            const float4 bL = ((const float4*)b2)[ql * 2];
            const float4 bH = ((const float4*)b2)[ql * 2 + 1];
            float4 o1, o2;
            o1.x = fmaf(a[0], nd, bL.x); o1.y = fmaf(a[1], nd, bL.y);
            o1.z = fmaf(a[2], nd, bL.z); o1.w = fmaf(a[3], nd, bL.w);
            o2.x = fmaf(a[4], nd, bH.x); o2.y = fmaf(a[5], nd, bH.y);
            o2.z = fmaf(a[6], nd, bH.z); o2.w = fmaf(a[7], nd, bH.w);
            float* orow = out + (long)node * 32 + ql * 8;
            ((float4*)orow)[0] = o1;
            ((float4*)orow)[1] = o2;
        }
    }
}

extern "C" void kernel_launch(void* const* d_in, const int* in_sizes, int n_in,
                              void* d_out, int out_size, void* d_ws, size_t ws_size,
                              hipStream_t stream) {
    const float* x   = (const float*)d_in[0];
    const int*   src = (const int*)d_in[1];
    const int*   dst = (const int*)d_in[2];
    const float* W1  = (const float*)d_in[3];
    const float* b1  = (const float*)d_in[4];
    const float* W2  = (const float*)d_in[5];
    const float* b2  = (const float*)d_in[6];

    const int N = N_NODES;
    const int E = in_sizes[1];   // 1,600,000

    // workspace (int offsets; all gather/row buffers 64B-aligned):
    int* ws_i    = (int*)d_ws;
    int* sb_cnt  = ws_i;                           // [512]; reused as deg bins+cursors
    int* db_cnt  = ws_i + 512;
    int* sb_base = ws_i + 1024;
    int* db_base = ws_i + 1536;
    int* sb_cur  = ws_i + 2048;
    int* db_cur  = ws_i + 2560;
    int* rowptr  = ws_i + 3072;                    // [N+1, padded to 100032]
    int* colidx  = ws_i + 103104;                  // [E]
    float* norms = (float*)(ws_i + 1703104);       // [2N]
    int* ebuf    = ws_i + 1903104;                 // [E] ints, 64B-aligned (ybf overlay)
    unsigned char* sbuf = (unsigned char*)(ws_i + 3503104);   // [E] bytes
    unsigned short* xsb = (unsigned short*)(ws_i + 3903104);  // [32N] bf16, 64B-aligned
    float* agg   = (float*)(ws_i + 5503104);       // [32N] f32
    int* perm    = ws_i + 8703104;                 // [N]
    unsigned short* ybf = (unsigned short*)ebuf;

    zero_counts_kernel<<<4, 256, 0, stream>>>(ws_i);

    bucket_hist_kernel<<<256, 256, 0, stream>>>(src, dst, sb_cnt, db_cnt, E);
    bucket_scan_kernel<<<1, 512, 0, stream>>>(sb_cnt, db_cnt, sb_base, db_base,
                                              sb_cur, db_cur, E);

    int pb = (E + CHUNK - 1) / CHUNK;      // 196 blocks
    partition_both_kernel<<<pb, 512, 0, stream>>>(src, dst, sb_cur, db_cur,
                                                  ebuf, sbuf, E);
    bucket_finalize_kernel<<<NBUCK, 256, 0, stream>>>(sbuf, sb_base,
                                                      (const float4*)x, (ushort4v*)xsb,
                                                      norms, ebuf, db_base, rowptr,
                                                      norms + N, colidx, N, E);

    deg_hist_kernel<<<NBUCK, 256, 0, stream>>>(rowptr, sb_cnt, N);
    deg_scan_kernel<<<1, 256, 0, stream>>>(sb_cnt);
    place_perm_kernel<<<NBUCK, 256, 0, stream>>>(rowptr, sb_cnt, perm, N);

    gather1_kernel<<<2048, 256, 0, stream>>>((const ushort8v*)xsb, colidx, rowptr,
                                             perm, agg, N);
    gemm_fused_kernel<<<2048, 256, 0, stream>>>(agg, norms, norms + N,
                                                W1, b1, W2, ybf, N);
    gather2_kernel<<<2048, 256, 0, stream>>>((const ushort8v*)ybf, colidx, rowptr,
                                             perm, norms + N, b2, (float*)d_out, N);
}

// Round 17
// 163.150 us; speedup vs baseline: 2.6581x; 1.1055x over previous
//
#include <hip/hip_runtime.h>

#define N_NODES 100000
#define D_IN 32
#define D_HID 64
#define D_OUT 32
#define NBUCK 391      // ceil(N_NODES/256)
#define CHUNK 8192     // edges per partition block
#define CAP   8192     // localfill LDS image capacity (ints)

typedef unsigned short ushort8v __attribute__((ext_vector_type(8)));
typedef unsigned short ushort4v __attribute__((ext_vector_type(4)));

__device__ __forceinline__ float bf2f(unsigned short u) {
    return __uint_as_float((unsigned)u << 16);
}
__device__ __forceinline__ unsigned short f2bf(float f) {
    unsigned u = __float_as_uint(f);
    return (unsigned short)((u + 0x7FFF + ((u >> 16) & 1)) >> 16);   // RTN-even
}

// ---------------- zero the 1024 bucket counters ----------------
__global__ void zero_counts_kernel(int* __restrict__ p) {
    p[blockIdx.x * 256 + threadIdx.x] = 0;
}

// ---------------- bucket-level histograms (LDS-staged) ----------------
__global__ __launch_bounds__(256) void bucket_hist_kernel(
    const int* __restrict__ src, const int* __restrict__ dst,
    int* __restrict__ sb_cnt, int* __restrict__ db_cnt, int E) {
    __shared__ int hs[NBUCK], hd[NBUCK];
    int tid = threadIdx.x;
    for (int i = tid; i < NBUCK; i += 256) { hs[i] = 0; hd[i] = 0; }
    __syncthreads();
    int stride = gridDim.x * 256;
    for (int e = blockIdx.x * 256 + tid; e < E; e += stride) {
        atomicAdd(&hs[src[e] >> 8], 1);
        atomicAdd(&hd[dst[e] >> 8], 1);
    }
    __syncthreads();
    for (int i = tid; i < NBUCK; i += 256) {
        if (hs[i]) atomicAdd(&sb_cnt[i], hs[i]);
        if (hd[i]) atomicAdd(&db_cnt[i], hd[i]);
    }
}

// ---------------- single-block scan of both bucket counters ----------------
__global__ __launch_bounds__(512) void bucket_scan_kernel(
    const int* __restrict__ sb_cnt, const int* __restrict__ db_cnt,
    int* __restrict__ sb_base, int* __restrict__ db_base,
    int* __restrict__ sb_cur, int* __restrict__ db_cur, int E) {
    __shared__ int s[512];
    int tid = threadIdx.x;
    int v = (tid < NBUCK) ? sb_cnt[tid] : 0;
    s[tid] = v;
    __syncthreads();
    for (int off = 1; off < 512; off <<= 1) {
        int tv = (tid >= off) ? s[tid - off] : 0;
        __syncthreads(); s[tid] += tv; __syncthreads();
    }
    if (tid < NBUCK) { int e0 = s[tid] - v; sb_base[tid] = e0; sb_cur[tid] = e0; }
    if (tid == 0) sb_base[NBUCK] = E;
    __syncthreads();
    int v2 = (tid < NBUCK) ? db_cnt[tid] : 0;
    s[tid] = v2;
    __syncthreads();
    for (int off = 1; off < 512; off <<= 1) {
        int tv = (tid >= off) ? s[tid - off] : 0;
        __syncthreads(); s[tid] += tv; __syncthreads();
    }
    if (tid < NBUCK) { int e0 = s[tid] - v2; db_base[tid] = e0; db_cur[tid] = e0; }
    if (tid == 0) db_base[NBUCK] = E;
}

// ---------------- merged LDS multisplit: dst->ebuf (packed), src->sbuf (bytes) ----------------
__global__ __launch_bounds__(512) void partition_both_kernel(
    const int* __restrict__ src, const int* __restrict__ dst,
    int* __restrict__ sb_cur, int* __restrict__ db_cur,
    int* __restrict__ ebuf, unsigned char* __restrict__ sbuf, int E) {
    __shared__ int dh[NBUCK], sh_[NBUCK];
    __shared__ int sarr[512];
    __shared__ int dloff[NBUCK], dgb[NBUCK], dcur[NBUCK];
    __shared__ int sloff[NBUCK], sgb[NBUCK], scur[NBUCK];
    __shared__ int dbuf[CHUNK];
    __shared__ unsigned char sbytes[CHUNK];
    int tid = threadIdx.x;
    int base = blockIdx.x * CHUNK;
    int lim = E - base; if (lim > CHUNK) lim = CHUNK;

    for (int i = tid; i < NBUCK; i += 512) { dh[i] = 0; sh_[i] = 0; }
    __syncthreads();
    for (int k = tid; k < lim; k += 512) {
        atomicAdd(&dh[dst[base + k] >> 8], 1);
        atomicAdd(&sh_[src[base + k] >> 8], 1);
    }
    __syncthreads();
    int v = (tid < NBUCK) ? dh[tid] : 0;
    sarr[tid] = v;
    __syncthreads();
    for (int off = 1; off < 512; off <<= 1) {
        int tv = (tid >= off) ? sarr[tid - off] : 0;
        __syncthreads(); sarr[tid] += tv; __syncthreads();
    }
    if (tid < NBUCK) {
        int excl = sarr[tid] - v;
        dloff[tid] = excl; dcur[tid] = excl;
        dgb[tid] = v ? atomicAdd(&db_cur[tid], v) : 0;
    }
    __syncthreads();
    int v2 = (tid < NBUCK) ? sh_[tid] : 0;
    sarr[tid] = v2;
    __syncthreads();
    for (int off = 1; off < 512; off <<= 1) {
        int tv = (tid >= off) ? sarr[tid - off] : 0;
        __syncthreads(); sarr[tid] += tv; __syncthreads();
    }
    if (tid < NBUCK) {
        int excl = sarr[tid] - v2;
        sloff[tid] = excl; scur[tid] = excl;
        sgb[tid] = v2 ? atomicAdd(&sb_cur[tid], v2) : 0;
    }
    __syncthreads();
    for (int k = tid; k < lim; k += 512) {
        int d = dst[base + k], s0 = src[base + k];
        int p = atomicAdd(&dcur[d >> 8], 1);
        dbuf[p] = (s0 << 8) | (d & 255);
        int p2 = atomicAdd(&scur[s0 >> 8], 1);
        sbytes[p2] = (unsigned char)(s0 & 255);
    }
    __syncthreads();
    int w = tid >> 6, lane = tid & 63;
    for (int b = w; b < NBUCK; b += 8) {
        int st = dloff[b], len = dh[b], gb = dgb[b];
        for (int i = lane; i < len; i += 64) ebuf[gb + i] = dbuf[st + i];
        int st2 = sloff[b], len2 = sh_[b], gb2 = sgb[b];
        for (int i = lane; i < len2; i += 64) sbuf[gb2 + i] = sbytes[st2 + i];
    }
}

// ---------------- per-bucket finalize: norms + prescale + rowptr + colidx ----------------
__global__ __launch_bounds__(256) void bucket_finalize_kernel(
    const unsigned char* __restrict__ sbuf, const int* __restrict__ sb_base,
    const float4* __restrict__ x4, ushort4v* __restrict__ xs4b,
    float* __restrict__ norm_src,
    const int* __restrict__ ebuf, const int* __restrict__ db_base,
    int* __restrict__ rowptr, float* __restrict__ norm_dst,
    int* __restrict__ colidx, int n_nodes, int E) {
    __shared__ int limg[CAP];
    __shared__ int cnt[256];
    __shared__ int sc[256];
    __shared__ float nsl[256];
    int b = blockIdx.x, tid = threadIdx.x;
    int base_node = b << 8;
    int nn = n_nodes - base_node; if (nn > 256) nn = 256;

    // ---- phase 1: src degree -> norm_src + xs prescale ----
    int st = sb_base[b], en = sb_base[b + 1];
    cnt[tid] = 0;
    __syncthreads();
    for (int k = st + tid; k < en; k += 256) atomicAdd(&cnt[sbuf[k]], 1);
    __syncthreads();
    if (tid < nn) {
        int d = cnt[tid];
        float ns = rsqrtf((float)(d < 1 ? 1 : d));
        norm_src[base_node + tid] = ns;
        nsl[tid] = ns;
    }
    __syncthreads();
    for (int k = tid; k < nn * 8; k += 256) {
        float4 v = x4[((long)base_node << 3) + k];
        float s = nsl[k >> 3];
        ushort4v o;
        o[0] = f2bf(v.x * s); o[1] = f2bf(v.y * s);
        o[2] = f2bf(v.z * s); o[3] = f2bf(v.w * s);
        xs4b[((long)base_node << 3) + k] = o;
    }

    // ---- phase 2: dst degree -> rowptr/norm_dst, colidx fill ----
    int cbase = db_base[b], cend = db_base[b + 1];
    int len = cend - cbase;
    __syncthreads();
    cnt[tid] = 0;
    __syncthreads();
    for (int k = tid; k < len; k += 256) atomicAdd(&cnt[ebuf[cbase + k] & 255], 1);
    __syncthreads();
    int v = cnt[tid];
    sc[tid] = v;
    __syncthreads();
    for (int off = 1; off < 256; off <<= 1) {
        int tv = (tid >= off) ? sc[tid - off] : 0;
        __syncthreads(); sc[tid] += tv; __syncthreads();
    }
    int excl = sc[tid] - v;
    if (tid < nn) {
        rowptr[base_node + tid] = cbase + excl;
        norm_dst[base_node + tid] = rsqrtf((float)(v < 1 ? 1 : v));
    }
    if (b == NBUCK - 1 && tid == 0) rowptr[n_nodes] = E;
    __syncthreads();
    cnt[tid] = excl;   // reuse as local cursor
    __syncthreads();
    if (len <= CAP) {
        for (int k = tid; k < len; k += 256) {
            int v2 = ebuf[cbase + k];
            int p = atomicAdd(&cnt[v2 & 255], 1);
            limg[p] = v2 >> 8;
        }
        __syncthreads();
        for (int k = tid; k < len; k += 256) colidx[cbase + k] = limg[k];
    } else {
        for (int k = tid; k < len; k += 256) {
            int v2 = ebuf[cbase + k];
            int p = atomicAdd(&cnt[v2 & 255], 1);
            colidx[cbase + p] = v2 >> 8;
        }
    }
}

// ---------------- pure gather 1: 4 nodes/wave (quarter-wave each) -> agg f32 ----------------
// quarter = lane>>4 (node); ql = lane&15; eh = ql>>2 (slot 0..3); q = ql&3 (16B chunk)
__global__ __launch_bounds__(256) void gather1_kernel(
    const ushort8v* __restrict__ xs8, const int* __restrict__ colidx,
    const int* __restrict__ rowptr, float* __restrict__ agg, int n_nodes) {
    int t = threadIdx.x;
    int w = t >> 6, lane = t & 63;
    int quarter = lane >> 4, ql = lane & 15;
    int eh = ql >> 2, q = ql & 3;
    int qb = quarter << 4;
    int nquads = (n_nodes + 3) >> 2;

    for (int p = blockIdx.x * 4 + w; p < nquads; p += gridDim.x * 4) {
        int base_node = p << 2;
        int idx = base_node + lane;
        if (idx > n_nodes) idx = n_nodes;
        int rr = (lane < 5) ? rowptr[idx] : 0;
        int myS = __shfl(rr, quarter);
        int myE = __shfl(rr, quarter + 1);
        int myD = myE - myS;
        int dm = myD;
        dm = max(dm, __shfl_xor(dm, 16));
        dm = max(dm, __shfl_xor(dm, 32));
        float a[8];
#pragma unroll
        for (int r = 0; r < 8; ++r) a[r] = 0.f;
        for (int base = 0; base < dm; base += 16) {
            int mylim = myD - base; mylim = mylim < 0 ? 0 : (mylim > 16 ? 16 : mylim);
            int c_reg = (ql < mylim) ? colidx[myS + base + ql] : 0;
            int c0 = __shfl(c_reg, qb | eh);
            int c1 = __shfl(c_reg, qb | (eh + 4));
            int c2 = __shfl(c_reg, qb | (eh + 8));
            int c3 = __shfl(c_reg, qb | (eh + 12));
            ushort8v v0 = xs8[(long)c0 * 4 + q];
            ushort8v v1 = xs8[(long)c1 * 4 + q];
            ushort8v v2 = xs8[(long)c2 * 4 + q];
            ushort8v v3 = xs8[(long)c3 * 4 + q];
            float m0 = (eh      < mylim) ? 1.f : 0.f;
            float m1 = (eh +  4 < mylim) ? 1.f : 0.f;
            float m2 = (eh +  8 < mylim) ? 1.f : 0.f;
            float m3 = (eh + 12 < mylim) ? 1.f : 0.f;
#pragma unroll
            for (int r = 0; r < 8; ++r) {
                a[r] = fmaf(bf2f(v0[r]), m0, a[r]);
                a[r] = fmaf(bf2f(v1[r]), m1, a[r]);
                a[r] = fmaf(bf2f(v2[r]), m2, a[r]);
                a[r] = fmaf(bf2f(v3[r]), m3, a[r]);
            }
        }
#pragma unroll
        for (int r = 0; r < 8; ++r) { a[r] += __shfl_xor(a[r], 4); a[r] += __shfl_xor(a[r], 8); }
        if (ql < 4) {                       // eh==0 lanes; chunk = ql
            int n_ = base_node + quarter;
            if (n_ < n_nodes) {
                float* orow = agg + (long)n_ * 32 + ql * 8;
                float4 o1, o2;
                o1.x = a[0]; o1.y = a[1]; o1.z = a[2]; o1.w = a[3];
                o2.x = a[4]; o2.y = a[5]; o2.z = a[6]; o2.w = a[7];
                ((float4*)orow)[0] = o1;
                ((float4*)orow)[1] = o2;
            }
        }
    }
}

// ---------------- dense fused GEMMs: ybf = bf16( ns * ((nd*(agg@W1)+b1) @ W2) ) ----------------
__global__ __launch_bounds__(256) void gemm_fused_kernel(
    const float* __restrict__ agg, const float* __restrict__ norm_src,
    const float* __restrict__ norm_dst,
    const float* __restrict__ W1, const float* __restrict__ b1,
    const float* __restrict__ W2, unsigned short* __restrict__ ybf, int n_nodes) {
    __shared__ float W1s[D_IN * D_HID];
    __shared__ float W2s[D_HID * D_OUT];
    __shared__ float b1s[D_HID];
    __shared__ float accs[4][2][D_IN];
    __shared__ float z1s[4][2][D_HID];
    int t = threadIdx.x;
    for (int i = t; i < 2048; i += 256) { W1s[i] = W1[i]; W2s[i] = W2[i]; }
    if (t < D_HID) b1s[t] = b1[t];
    __syncthreads();
    int w = t >> 6, lane = t & 63;
    int half = lane >> 5, hl = lane & 31;
    int npairs = (n_nodes + 1) >> 1;
    for (int p = blockIdx.x * 4 + w; p < npairs; p += gridDim.x * 4) {
        int nA = 2 * p, nB = nA + 1;
        bool hasB = nB < n_nodes;
        int nh = half ? (hasB ? nB : nA) : nA;
        accs[w][half][hl] = agg[(long)nh * 32 + hl];   // same-wave LDS
        float ndA = norm_dst[nA], ndB = hasB ? norm_dst[nB] : 0.f;
        float s1A = 0.f, s1B = 0.f;
#pragma unroll
        for (int k = 0; k < D_IN; ++k) {
            float wv = W1s[k * D_HID + lane];
            s1A = fmaf(accs[w][0][k], wv, s1A);
            s1B = fmaf(accs[w][1][k], wv, s1B);
        }
        z1s[w][0][lane] = ndA * s1A + b1s[lane];
        z1s[w][1][lane] = ndB * s1B + b1s[lane];
        float s2 = 0.f;
#pragma unroll
        for (int k = 0; k < D_HID; ++k) s2 = fmaf(z1s[w][half][k], W2s[k * D_OUT + hl], s2);
        int n_ = half ? nB : nA;
        if (!half || hasB) ybf[(long)n_ * 32 + hl] = f2bf(norm_src[n_] * s2);
    }
}

// ---------------- pure gather 2: 4 nodes/wave -> out = nd*sum + b2 ----------------
__global__ __launch_bounds__(256) void gather2_kernel(
    const ushort8v* __restrict__ y8, const int* __restrict__ colidx,
    const int* __restrict__ rowptr, const float* __restrict__ norm_dst,
    const float* __restrict__ b2, float* __restrict__ out, int n_nodes) {
    int t = threadIdx.x;
    int w = t >> 6, lane = t & 63;
    int quarter = lane >> 4, ql = lane & 15;
    int eh = ql >> 2, q = ql & 3;
    int qb = quarter << 4;
    int nquads = (n_nodes + 3) >> 2;

    for (int p = blockIdx.x * 4 + w; p < nquads; p += gridDim.x * 4) {
        int base_node = p << 2;
        int idx = base_node + lane;
        if (idx > n_nodes) idx = n_nodes;
        int rr = (lane < 5) ? rowptr[idx] : 0;
        int myS = __shfl(rr, quarter);
        int myE = __shfl(rr, quarter + 1);
        int myD = myE - myS;
        int dm = myD;
        dm = max(dm, __shfl_xor(dm, 16));
        dm = max(dm, __shfl_xor(dm, 32));
        float a[8];
#pragma unroll
        for (int r = 0; r < 8; ++r) a[r] = 0.f;
        for (int base = 0; base < dm; base += 16) {
            int mylim = myD - base; mylim = mylim < 0 ? 0 : (mylim > 16 ? 16 : mylim);
            int c_reg = (ql < mylim) ? colidx[myS + base + ql] : 0;
            int c0 = __shfl(c_reg, qb | eh);
            int c1 = __shfl(c_reg, qb | (eh + 4));
            int c2 = __shfl(c_reg, qb | (eh + 8));
            int c3 = __shfl(c_reg, qb | (eh + 12));
            ushort8v v0 = y8[(long)c0 * 4 + q];
            ushort8v v1 = y8[(long)c1 * 4 + q];
            ushort8v v2 = y8[(long)c2 * 4 + q];
            ushort8v v3 = y8[(long)c3 * 4 + q];
            float m0 = (eh      < mylim) ? 1.f : 0.f;
            float m1 = (eh +  4 < mylim) ? 1.f : 0.f;
            float m2 = (eh +  8 < mylim) ? 1.f : 0.f;
            float m3 = (eh + 12 < mylim) ? 1.f : 0.f;
#pragma unroll
            for (int r = 0; r < 8; ++r) {
                a[r] = fmaf(bf2f(v0[r]), m0, a[r]);
                a[r] = fmaf(bf2f(v1[r]), m1, a[r]);
                a[r] = fmaf(bf2f(v2[r]), m2, a[r]);
                a[r] = fmaf(bf2f(v3[r]), m3, a[r]);
            }
        }
#pragma unroll
        for (int r = 0; r < 8; ++r) { a[r] += __shfl_xor(a[r], 4); a[r] += __shfl_xor(a[r], 8); }
        if (ql < 4) {
            int n_ = base_node + quarter;
            if (n_ < n_nodes) {
                float nd = norm_dst[n_];
                const float4 bL = ((const float4*)b2)[ql * 2];
                const float4 bH = ((const float4*)b2)[ql * 2 + 1];
                float4 o1, o2;
                o1.x = fmaf(a[0], nd, bL.x); o1.y = fmaf(a[1], nd, bL.y);
                o1.z = fmaf(a[2], nd, bL.z); o1.w = fmaf(a[3], nd, bL.w);
                o2.x = fmaf(a[4], nd, bH.x); o2.y = fmaf(a[5], nd, bH.y);
                o2.z = fmaf(a[6], nd, bH.z); o2.w = fmaf(a[7], nd, bH.w);
                float* orow = out + (long)n_ * 32 + ql * 8;
                ((float4*)orow)[0] = o1;
                ((float4*)orow)[1] = o2;
            }
        }
    }
}

extern "C" void kernel_launch(void* const* d_in, const int* in_sizes, int n_in,
                              void* d_out, int out_size, void* d_ws, size_t ws_size,
                              hipStream_t stream) {
    const float* x   = (const float*)d_in[0];
    const int*   src = (const int*)d_in[1];
    const int*   dst = (const int*)d_in[2];
    const float* W1  = (const float*)d_in[3];
    const float* b1  = (const float*)d_in[4];
    const float* W2  = (const float*)d_in[5];
    const float* b2  = (const float*)d_in[6];

    const int N = N_NODES;
    const int E = in_sizes[1];   // 1,600,000

    // workspace (int offsets; all gather/row buffers 64B-aligned):
    int* ws_i    = (int*)d_ws;
    int* sb_cnt  = ws_i;
    int* db_cnt  = ws_i + 512;
    int* sb_base = ws_i + 1024;
    int* db_base = ws_i + 1536;
    int* sb_cur  = ws_i + 2048;
    int* db_cur  = ws_i + 2560;
    int* rowptr  = ws_i + 3072;                    // [N+1, padded to 100032]
    int* colidx  = ws_i + 103104;                  // [E]
    float* norms = (float*)(ws_i + 1703104);       // [2N]
    int* ebuf    = ws_i + 1903104;                 // [E] ints, 64B-aligned (ybf overlay)
    unsigned char* sbuf = (unsigned char*)(ws_i + 3503104);   // [E] bytes
    unsigned short* xsb = (unsigned short*)(ws_i + 3903104);  // [32N] bf16, 64B-aligned
    float* agg   = (float*)(ws_i + 5503104);       // [32N] f32
    unsigned short* ybf = (unsigned short*)ebuf;

    zero_counts_kernel<<<4, 256, 0, stream>>>(ws_i);

    bucket_hist_kernel<<<256, 256, 0, stream>>>(src, dst, sb_cnt, db_cnt, E);
    bucket_scan_kernel<<<1, 512, 0, stream>>>(sb_cnt, db_cnt, sb_base, db_base,
                                              sb_cur, db_cur, E);

    int pb = (E + CHUNK - 1) / CHUNK;      // 196 blocks
    partition_both_kernel<<<pb, 512, 0, stream>>>(src, dst, sb_cur, db_cur,
                                                  ebuf, sbuf, E);
    bucket_finalize_kernel<<<NBUCK, 256, 0, stream>>>(sbuf, sb_base,
                                                      (const float4*)x, (ushort4v*)xsb,
                                                      norms, ebuf, db_base, rowptr,
                                                      norms + N, colidx, N, E);

    gather1_kernel<<<2048, 256, 0, stream>>>((const ushort8v*)xsb, colidx, rowptr,
                                             agg, N);
    gemm_fused_kernel<<<2048, 256, 0, stream>>>(agg, norms, norms + N,
                                                W1, b1, W2, ybf, N);
    gather2_kernel<<<2048, 256, 0, stream>>>((const ushort8v*)ybf, colidx, rowptr,
                                             norms + N, b2, (float*)d_out, N);
}